// Round 1
// baseline (416.029 us; speedup 1.0000x reference)
//
#include <hip/hip_runtime.h>

// Problem dims (fixed by setup_inputs)
constexpr int NB = 128;   // batch
constexpr int NS = 512;   // seq len
constexpr int NH = 768;   // hidden
constexpr int NT = 3;     // tags

__device__ __forceinline__ float lse3(float x0, float x1, float x2) {
    float m = fmaxf(x0, fmaxf(x1, x2));
    return m + __logf(__expf(x0 - m) + __expf(x1 - m) + __expf(x2 - m));
}

// prediction[b,s,t] = dot(inputs[b,s,:], W[t,:]) + b[t]
// One wave per row (b,s). 768 = 64 lanes * 3 float4.
__global__ __launch_bounds__(256) void pred_kernel(
    const float* __restrict__ x, const float* __restrict__ W,
    const float* __restrict__ bias, float* __restrict__ out)
{
    const int lane = threadIdx.x & 63;
    const int row  = blockIdx.x * (blockDim.x >> 6) + (threadIdx.x >> 6);

    // W fragments: W row t is 768 floats = 192 float4; chunk c covers 64 float4.
    const float4* W4 = (const float4*)W;
    float4 w[3][3];
#pragma unroll
    for (int t = 0; t < 3; ++t)
#pragma unroll
        for (int c = 0; c < 3; ++c)
            w[t][c] = W4[t * 192 + c * 64 + lane];

    const float4* X4 = (const float4*)(x + (size_t)row * NH);
    float acc0 = 0.f, acc1 = 0.f, acc2 = 0.f;
#pragma unroll
    for (int c = 0; c < 3; ++c) {
        float4 v = X4[c * 64 + lane];
        acc0 += v.x * w[0][c].x + v.y * w[0][c].y + v.z * w[0][c].z + v.w * w[0][c].w;
        acc1 += v.x * w[1][c].x + v.y * w[1][c].y + v.z * w[1][c].z + v.w * w[1][c].w;
        acc2 += v.x * w[2][c].x + v.y * w[2][c].y + v.z * w[2][c].z + v.w * w[2][c].w;
    }
#pragma unroll
    for (int off = 32; off >= 1; off >>= 1) {
        acc0 += __shfl_xor(acc0, off, 64);
        acc1 += __shfl_xor(acc1, off, 64);
        acc2 += __shfl_xor(acc2, off, 64);
    }
    if (lane < 3) {
        float a = (lane == 0) ? acc0 : ((lane == 1) ? acc1 : acc2);
        out[(size_t)row * 3 + lane] = a + bias[lane];
    }
}

// CRF loss: one thread per batch, sequential forward recursion over S.
__global__ __launch_bounds__(128) void crf_kernel(
    const float* __restrict__ feats, const int* __restrict__ y,
    const float* __restrict__ trans, const float* __restrict__ startt,
    const float* __restrict__ stopt, float* __restrict__ loss_out)
{
    __shared__ float sTr[9];
    __shared__ float partial[2];
    if (threadIdx.x < 9) sTr[threadIdx.x] = trans[threadIdx.x];
    __syncthreads();

    const int b = threadIdx.x;  // 0..127
    const float T00 = sTr[0], T01 = sTr[1], T02 = sTr[2];
    const float T10 = sTr[3], T11 = sTr[4], T12 = sTr[5];
    const float T20 = sTr[6], T21 = sTr[7], T22 = sTr[8];
    const float st0 = startt[0], st1 = startt[1], st2 = startt[2];
    const float sp0 = stopt[0],  sp1 = stopt[1],  sp2 = stopt[2];

    const float* f  = feats + (size_t)b * NS * NT;
    const int*   yy = y + b * NS;

    float f0 = f[0], f1 = f[1], f2 = f[2];
    const int t0 = yy[0];
    float emit = (t0 == 0) ? f0 : ((t0 == 1) ? f1 : f2);
    float a0 = f0 + st0, a1 = f1 + st1, a2 = f2 + st2;
    float trs = 0.f;
    int prev = t0;

    for (int s = 1; s < NS; ++s) {
        f0 = f[s * 3 + 0]; f1 = f[s * 3 + 1]; f2 = f[s * 3 + 2];
        const int tg = yy[s];
        emit += (tg == 0) ? f0 : ((tg == 1) ? f1 : f2);
        trs  += sTr[prev * 3 + tg];
        prev = tg;
        const float n0 = f0 + lse3(a0 + T00, a1 + T10, a2 + T20);
        const float n1 = f1 + lse3(a0 + T01, a1 + T11, a2 + T21);
        const float n2 = f2 + lse3(a0 + T02, a1 + T12, a2 + T22);
        a0 = n0; a1 = n1; a2 = n2;
    }

    const float startsel = (t0 == 0) ? st0 : ((t0 == 1) ? st1 : st2);
    const float stopsel  = (prev == 0) ? sp0 : ((prev == 1) ? sp1 : sp2);
    const float seq  = emit + trs + startsel + stopsel;
    const float logz = lse3(a0 + sp0, a1 + sp1, a2 + sp2);
    float val = seq - logz;

#pragma unroll
    for (int off = 32; off >= 1; off >>= 1)
        val += __shfl_xor(val, off, 64);
    if ((threadIdx.x & 63) == 0) partial[threadIdx.x >> 6] = val;
    __syncthreads();
    if (threadIdx.x == 0)
        loss_out[0] = -(partial[0] + partial[1]) / (float)NB;
}

extern "C" void kernel_launch(void* const* d_in, const int* in_sizes, int n_in,
                              void* d_out, int out_size, void* d_ws, size_t ws_size,
                              hipStream_t stream)
{
    const float* x      = (const float*)d_in[0];
    const int*   y      = (const int*)d_in[1];   // harness delivers integer inputs as int32
    const float* W      = (const float*)d_in[2];
    const float* bias   = (const float*)d_in[3];
    const float* trans  = (const float*)d_in[4];
    const float* startt = (const float*)d_in[5];
    const float* stopt  = (const float*)d_in[6];

    float* out      = (float*)d_out;
    float* loss_out = out + (size_t)NB * NS * NT;  // element 196608

    const int rows = NB * NS;                // 65536 rows, 4 waves/block
    pred_kernel<<<rows / 4, 256, 0, stream>>>(x, W, bias, out);
    crf_kernel<<<1, 128, 0, stream>>>(out, y, trans, startt, stopt, loss_out);
}

// Round 2
// 321.803 us; speedup vs baseline: 1.2928x; 1.2928x over previous
//
#include <hip/hip_runtime.h>

constexpr int NB = 128;   // batch
constexpr int NS = 512;   // seq len
constexpr int NH = 768;   // hidden
constexpr int NT = 3;     // tags
constexpr int ROWS = NB * NS;      // 65536
constexpr int NCH = 64;            // chunks per sequence
constexpr int CHL = 8;             // steps per chunk (chunk 0 has 7: steps 1..7)
constexpr float NEG = -1e30f;

__device__ __forceinline__ float lse3(float x0, float x1, float x2) {
    float m = fmaxf(x0, fmaxf(x1, x2));
    return m + __logf(__expf(x0 - m) + __expf(x1 - m) + __expf(x2 - m));
}

__device__ __forceinline__ float dot4(float4 a, float4 b) {
    return a.x * b.x + a.y * b.y + a.z * b.z + a.w * b.w;
}

// prediction[b,s,t] = dot(inputs[b,s,:], W[t,:]) + b[t]
// Grid-stride waves: W held in registers, rows streamed with pipelined loads.
__global__ __launch_bounds__(256) void pred_kernel(
    const float* __restrict__ x, const float* __restrict__ W,
    const float* __restrict__ bias, float* __restrict__ out)
{
    const int lane   = threadIdx.x & 63;
    const int nwaves = gridDim.x * 4;
    const int gw     = blockIdx.x * 4 + (threadIdx.x >> 6);

    const float4* W4 = (const float4*)W;
    float4 w[3][3];
#pragma unroll
    for (int t = 0; t < 3; ++t)
#pragma unroll
        for (int c = 0; c < 3; ++c)
            w[t][c] = W4[t * 192 + c * 64 + lane];
    const float b0 = bias[0], b1 = bias[1], b2 = bias[2];

    const float4* X4 = (const float4*)x;
    int row = gw;
    if (row >= ROWS) return;
    int base = row * 192 + lane;
    float4 v0 = X4[base], v1 = X4[base + 64], v2 = X4[base + 128];

    while (true) {
        const int nrow = row + nwaves;
        const bool more = nrow < ROWS;
        float4 t0, t1, t2;
        if (more) {             // issue next row's loads before the reduce
            const int nb = nrow * 192 + lane;
            t0 = X4[nb]; t1 = X4[nb + 64]; t2 = X4[nb + 128];
        }
        float acc0 = dot4(v0, w[0][0]) + dot4(v1, w[0][1]) + dot4(v2, w[0][2]);
        float acc1 = dot4(v0, w[1][0]) + dot4(v1, w[1][1]) + dot4(v2, w[1][2]);
        float acc2 = dot4(v0, w[2][0]) + dot4(v1, w[2][1]) + dot4(v2, w[2][2]);
#pragma unroll
        for (int off = 32; off >= 1; off >>= 1) {
            acc0 += __shfl_xor(acc0, off, 64);
            acc1 += __shfl_xor(acc1, off, 64);
            acc2 += __shfl_xor(acc2, off, 64);
        }
        if (lane < 3) {
            float a = (lane == 0) ? acc0 + b0 : ((lane == 1) ? acc1 + b1 : acc2 + b2);
            out[(size_t)row * 3 + lane] = a;
        }
        if (!more) break;
        v0 = t0; v1 = t1; v2 = t2; row = nrow;
    }
}

// Stage A: per (batch, chunk, init-state) compute the chunk's log-semiring
// transfer matrix row M[e][j], plus per-chunk emit/trans score partials.
__global__ __launch_bounds__(256) void crf_scan_kernel(
    const float* __restrict__ feats, const int* __restrict__ y,
    const float* __restrict__ trans, float* __restrict__ ws_m,
    float* __restrict__ ws_p)
{
    __shared__ float sTr[9];
    if (threadIdx.x < 9) sTr[threadIdx.x] = trans[threadIdx.x];
    __syncthreads();

    const int gtid = blockIdx.x * 256 + threadIdx.x;   // < 128*64*3
    const int e  = gtid % 3;
    const int bc = gtid / 3;
    const int b  = bc >> 6;
    const int c  = bc & 63;

    const float T00 = sTr[0], T01 = sTr[1], T02 = sTr[2];
    const float T10 = sTr[3], T11 = sTr[4], T12 = sTr[5];
    const float T20 = sTr[6], T21 = sTr[7], T22 = sTr[8];

    const float* fb = feats + (size_t)b * NS * NT;
    const int*   yb = y + b * NS;

    float a0 = (e == 0) ? 0.f : NEG;
    float a1 = (e == 1) ? 0.f : NEG;
    float a2 = (e == 2) ? 0.f : NEG;

    const int s_begin = (c == 0) ? 1 : c * CHL;
    const int s_end   = c * CHL + CHL;

    float sc = 0.f;
    int prev = yb[s_begin - 1];
    if (c == 0) {  // emit at s=0
        float g0 = fb[0], g1 = fb[1], g2 = fb[2];
        sc = (prev == 0) ? g0 : ((prev == 1) ? g1 : g2);
    }

    for (int s = s_begin; s < s_end; ++s) {
        const float f0 = fb[s * 3], f1 = fb[s * 3 + 1], f2 = fb[s * 3 + 2];
        const int tg = yb[s];
        sc += ((tg == 0) ? f0 : ((tg == 1) ? f1 : f2)) + sTr[prev * 3 + tg];
        prev = tg;
        const float n0 = f0 + lse3(a0 + T00, a1 + T10, a2 + T20);
        const float n1 = f1 + lse3(a0 + T01, a1 + T11, a2 + T21);
        const float n2 = f2 + lse3(a0 + T02, a1 + T12, a2 + T22);
        a0 = n0; a1 = n1; a2 = n2;
    }

    // M row e for (b,c): 12-float slot, 16B-aligned float4 store
    float4* dst = (float4*)(ws_m + (size_t)(b * NCH + c) * 12) + e;
    *dst = make_float4(a0, a1, a2, 0.f);
    if (e == 0) ws_p[b * NCH + c] = sc;
}

// Stage B: per batch, fold 64 chunk matrices into alpha, finish loss.
__global__ __launch_bounds__(128) void crf_combine_kernel(
    const float* __restrict__ feats, const int* __restrict__ y,
    const float* __restrict__ ws_m, const float* __restrict__ ws_p,
    const float* __restrict__ startt, const float* __restrict__ stopt,
    float* __restrict__ loss_out)
{
    __shared__ float partial[2];
    const int b = threadIdx.x;

    const float st0 = startt[0], st1 = startt[1], st2 = startt[2];
    const float sp0 = stopt[0],  sp1 = stopt[1],  sp2 = stopt[2];

    const float* fb = feats + (size_t)b * NS * NT;
    float a0 = fb[0] + st0, a1 = fb[1] + st1, a2 = fb[2] + st2;

    const float4* M = (const float4*)(ws_m + (size_t)b * NCH * 12);
    const float*  P = ws_p + b * NCH;

    float4 m0 = M[0], m1 = M[1], m2 = M[2];
    float  pp = P[0];
    float  sc = 0.f;

#pragma unroll 4
    for (int c = 0; c < NCH; ++c) {
        float4 u0, u1, u2; float up;
        if (c < NCH - 1) {                 // prefetch next chunk
            u0 = M[(c + 1) * 3]; u1 = M[(c + 1) * 3 + 1]; u2 = M[(c + 1) * 3 + 2];
            up = P[c + 1];
        }
        sc += pp;
        const float n0 = lse3(a0 + m0.x, a1 + m1.x, a2 + m2.x);
        const float n1 = lse3(a0 + m0.y, a1 + m1.y, a2 + m2.y);
        const float n2 = lse3(a0 + m0.z, a1 + m1.z, a2 + m2.z);
        a0 = n0; a1 = n1; a2 = n2;
        m0 = u0; m1 = u1; m2 = u2; pp = up;
    }

    const float logz = lse3(a0 + sp0, a1 + sp1, a2 + sp2);
    const int y0 = y[b * NS], yl = y[b * NS + NS - 1];
    const float seq = sc + ((y0 == 0) ? st0 : ((y0 == 1) ? st1 : st2))
                         + ((yl == 0) ? sp0 : ((yl == 1) ? sp1 : sp2));
    float val = seq - logz;

#pragma unroll
    for (int off = 32; off >= 1; off >>= 1)
        val += __shfl_xor(val, off, 64);
    if ((threadIdx.x & 63) == 0) partial[threadIdx.x >> 6] = val;
    __syncthreads();
    if (threadIdx.x == 0)
        loss_out[0] = -(partial[0] + partial[1]) / (float)NB;
}

extern "C" void kernel_launch(void* const* d_in, const int* in_sizes, int n_in,
                              void* d_out, int out_size, void* d_ws, size_t ws_size,
                              hipStream_t stream)
{
    const float* x      = (const float*)d_in[0];
    const int*   y      = (const int*)d_in[1];
    const float* W      = (const float*)d_in[2];
    const float* bias   = (const float*)d_in[3];
    const float* trans  = (const float*)d_in[4];
    const float* startt = (const float*)d_in[5];
    const float* stopt  = (const float*)d_in[6];

    float* out      = (float*)d_out;
    float* loss_out = out + (size_t)NB * NS * NT;

    float* ws_m = (float*)d_ws;                        // 128*64*12 floats = 384 KB
    float* ws_p = ws_m + (size_t)NB * NCH * 12;        // 128*64 floats   = 32 KB

    pred_kernel<<<1024, 256, 0, stream>>>(x, W, bias, out);
    crf_scan_kernel<<<(NB * NCH * 3) / 256, 256, 0, stream>>>(out, y, trans, ws_m, ws_p);
    crf_combine_kernel<<<1, 128, 0, stream>>>(out, y, ws_m, ws_p, startt, stopt, loss_out);
}

// Round 3
// 321.477 us; speedup vs baseline: 1.2941x; 1.0010x over previous
//
#include <hip/hip_runtime.h>

constexpr int NB = 128;   // batch
constexpr int NS = 512;   // seq len
constexpr int NH = 768;   // hidden
constexpr int NT = 3;     // tags
constexpr int ROWS = NB * NS;      // 65536
constexpr int NCH = 64;            // chunks per sequence
constexpr int CHL = 8;             // steps per chunk
constexpr float NEG = -1e30f;

__device__ __forceinline__ float lse3(float x0, float x1, float x2) {
    float m = fmaxf(x0, fmaxf(x1, x2));
    return m + __logf(__expf(x0 - m) + __expf(x1 - m) + __expf(x2 - m));
}

__device__ __forceinline__ float dot4(float4 a, float4 b) {
    return a.x * b.x + a.y * b.y + a.z * b.z + a.w * b.w;
}

__device__ __forceinline__ float sel3(int t, float a, float b, float c) {
    return (t == 0) ? a : ((t == 1) ? b : c);
}

// prediction[b,s,t] = dot(inputs[b,s,:], W[t,:]) + b[t]
// One wave per 2 rows per iteration: 6 outstanding float4 loads/lane,
// interleaved butterflies. W held in registers (9 float4).
__global__ __launch_bounds__(256) void pred_kernel(
    const float* __restrict__ x, const float* __restrict__ W,
    const float* __restrict__ bias, float* __restrict__ out)
{
    const int lane = threadIdx.x & 63;
    const int gw   = blockIdx.x * 4 + (threadIdx.x >> 6);
    const int nw   = gridDim.x * 4;          // 4096 waves
    const int stride = nw * 2;               // rows per sweep

    const float4* W4 = (const float4*)W;
    float4 w[3][3];
#pragma unroll
    for (int t = 0; t < 3; ++t)
#pragma unroll
        for (int c = 0; c < 3; ++c)
            w[t][c] = W4[t * 192 + c * 64 + lane];
    const float b0 = bias[0], b1 = bias[1], b2 = bias[2];

    const float4* X4 = (const float4*)x;
    int row = gw * 2;
    if (row >= ROWS) return;

    float4 vA[3], vB[3];
    {
        const int ba = row * 192 + lane;
#pragma unroll
        for (int c = 0; c < 3; ++c) { vA[c] = X4[ba + c * 64]; vB[c] = X4[ba + 192 + c * 64]; }
    }

    while (true) {
        const int nrow = row + stride;
        const bool more = nrow < ROWS;
        float4 tA[3], tB[3];
        if (more) {
            const int nb = nrow * 192 + lane;
#pragma unroll
            for (int c = 0; c < 3; ++c) { tA[c] = X4[nb + c * 64]; tB[c] = X4[nb + 192 + c * 64]; }
        }
        float a0 = dot4(vA[0], w[0][0]) + dot4(vA[1], w[0][1]) + dot4(vA[2], w[0][2]);
        float a1 = dot4(vA[0], w[1][0]) + dot4(vA[1], w[1][1]) + dot4(vA[2], w[1][2]);
        float a2 = dot4(vA[0], w[2][0]) + dot4(vA[1], w[2][1]) + dot4(vA[2], w[2][2]);
        float c0 = dot4(vB[0], w[0][0]) + dot4(vB[1], w[0][1]) + dot4(vB[2], w[0][2]);
        float c1 = dot4(vB[0], w[1][0]) + dot4(vB[1], w[1][1]) + dot4(vB[2], w[1][2]);
        float c2 = dot4(vB[0], w[2][0]) + dot4(vB[1], w[2][1]) + dot4(vB[2], w[2][2]);
#pragma unroll
        for (int off = 32; off >= 1; off >>= 1) {
            a0 += __shfl_xor(a0, off, 64);
            a1 += __shfl_xor(a1, off, 64);
            a2 += __shfl_xor(a2, off, 64);
            c0 += __shfl_xor(c0, off, 64);
            c1 += __shfl_xor(c1, off, 64);
            c2 += __shfl_xor(c2, off, 64);
        }
        if (lane < 6) {   // 6 contiguous floats: rows row, row+1
            float v = (lane == 0) ? a0 + b0 : (lane == 1) ? a1 + b1 : (lane == 2) ? a2 + b2
                    : (lane == 3) ? c0 + b0 : (lane == 4) ? c1 + b1 : c2 + b2;
            out[(size_t)row * 3 + lane] = v;
        }
        if (!more) break;
#pragma unroll
        for (int c = 0; c < 3; ++c) { vA[c] = tA[c]; vB[c] = tB[c]; }
        row = nrow;
    }
}

// Stage A: per (batch, chunk, init-state e): chunk transfer-matrix row +
// per-chunk gold-path partial score. Bulk register loads, no latency chain.
__global__ __launch_bounds__(256) void crf_scan_kernel(
    const float* __restrict__ feats, const int* __restrict__ y,
    const float* __restrict__ trans, float* __restrict__ ws_m,
    float* __restrict__ ws_p)
{
    __shared__ float sTr[9];
    if (threadIdx.x < 9) sTr[threadIdx.x] = trans[threadIdx.x];
    __syncthreads();

    const int gtid = blockIdx.x * 256 + threadIdx.x;   // < 128*64*3
    const int e  = gtid % 3;
    const int bc = gtid / 3;
    const int b  = bc >> 6;
    const int c  = bc & 63;

    const float T00 = sTr[0], T01 = sTr[1], T02 = sTr[2];
    const float T10 = sTr[3], T11 = sTr[4], T12 = sTr[5];
    const float T20 = sTr[6], T21 = sTr[7], T22 = sTr[8];

    const float* fb = feats + (size_t)b * NS * NT;
    const int*   yb = y + b * NS;

    // Bulk load: 24 feats (6 float4, 16B-aligned: c*96B) + 8 tags (2 int4)
    float ff[24];
    {
        float4* fv = (float4*)ff;
        const float4* src = (const float4*)(fb + c * CHL * NT);
#pragma unroll
        for (int i = 0; i < 6; ++i) fv[i] = src[i];
    }
    int yy[8];
    {
        int4* yv = (int4*)yy;
        const int4* ys = (const int4*)(yb + c * CHL);
        yv[0] = ys[0]; yv[1] = ys[1];
    }

    float a0 = (e == 0) ? 0.f : NEG;
    float a1 = (e == 1) ? 0.f : NEG;
    float a2 = (e == 2) ? 0.f : NEG;

    float sc = 0.f;
    int prev;
    if (c == 0) {
        prev = yy[0];
        sc = sel3(prev, ff[0], ff[1], ff[2]);   // emit at s=0
    } else {
        prev = yb[c * CHL - 1];
    }
    const int sl0 = (c == 0) ? 1 : 0;

#pragma unroll
    for (int sl = 0; sl < CHL; ++sl) {
        if (sl < sl0) continue;
        const float f0 = ff[sl * 3], f1 = ff[sl * 3 + 1], f2 = ff[sl * 3 + 2];
        const int tg = yy[sl];
        sc += sel3(tg, f0, f1, f2) + sTr[prev * 3 + tg];
        prev = tg;
        const float n0 = f0 + lse3(a0 + T00, a1 + T10, a2 + T20);
        const float n1 = f1 + lse3(a0 + T01, a1 + T11, a2 + T21);
        const float n2 = f2 + lse3(a0 + T02, a1 + T12, a2 + T22);
        a0 = n0; a1 = n1; a2 = n2;
    }

    float4* dst = (float4*)(ws_m + (size_t)(b * NCH + c) * 12) + e;
    *dst = make_float4(a0, a1, a2, 0.f);
    if (e == 0) ws_p[b * NCH + c] = sc;
}

// Stage B: per batch, fold 64 chunk matrices into alpha, finish loss.
__global__ __launch_bounds__(128) void crf_combine_kernel(
    const float* __restrict__ feats, const int* __restrict__ y,
    const float* __restrict__ ws_m, const float* __restrict__ ws_p,
    const float* __restrict__ startt, const float* __restrict__ stopt,
    float* __restrict__ loss_out)
{
    __shared__ float partial[2];
    const int b = threadIdx.x;

    const float st0 = startt[0], st1 = startt[1], st2 = startt[2];
    const float sp0 = stopt[0],  sp1 = stopt[1],  sp2 = stopt[2];

    const float* fb = feats + (size_t)b * NS * NT;
    float a0 = fb[0] + st0, a1 = fb[1] + st1, a2 = fb[2] + st2;

    const float4* M = (const float4*)(ws_m + (size_t)b * NCH * 12);
    const float*  P = ws_p + b * NCH;

    float4 m0 = M[0], m1 = M[1], m2 = M[2];
    float  pp = P[0];
    float  sc = 0.f;

#pragma unroll 4
    for (int c = 0; c < NCH; ++c) {
        float4 u0 = m0, u1 = m1, u2 = m2; float up = pp;
        if (c < NCH - 1) {                 // prefetch next chunk
            u0 = M[(c + 1) * 3]; u1 = M[(c + 1) * 3 + 1]; u2 = M[(c + 1) * 3 + 2];
            up = P[c + 1];
        }
        sc += pp;
        const float n0 = lse3(a0 + m0.x, a1 + m1.x, a2 + m2.x);
        const float n1 = lse3(a0 + m0.y, a1 + m1.y, a2 + m2.y);
        const float n2 = lse3(a0 + m0.z, a1 + m1.z, a2 + m2.z);
        a0 = n0; a1 = n1; a2 = n2;
        m0 = u0; m1 = u1; m2 = u2; pp = up;
    }

    const float logz = lse3(a0 + sp0, a1 + sp1, a2 + sp2);
    const int y0 = y[b * NS], yl = y[b * NS + NS - 1];
    const float seq = sc + ((y0 == 0) ? st0 : ((y0 == 1) ? st1 : st2))
                         + ((yl == 0) ? sp0 : ((yl == 1) ? sp1 : sp2));
    float val = seq - logz;

#pragma unroll
    for (int off = 32; off >= 1; off >>= 1)
        val += __shfl_xor(val, off, 64);
    if ((threadIdx.x & 63) == 0) partial[threadIdx.x >> 6] = val;
    __syncthreads();
    if (threadIdx.x == 0)
        loss_out[0] = -(partial[0] + partial[1]) / (float)NB;
}

extern "C" void kernel_launch(void* const* d_in, const int* in_sizes, int n_in,
                              void* d_out, int out_size, void* d_ws, size_t ws_size,
                              hipStream_t stream)
{
    const float* x      = (const float*)d_in[0];
    const int*   y      = (const int*)d_in[1];
    const float* W      = (const float*)d_in[2];
    const float* bias   = (const float*)d_in[3];
    const float* trans  = (const float*)d_in[4];
    const float* startt = (const float*)d_in[5];
    const float* stopt  = (const float*)d_in[6];

    float* out      = (float*)d_out;
    float* loss_out = out + (size_t)NB * NS * NT;

    float* ws_m = (float*)d_ws;                        // 128*64*12 floats
    float* ws_p = ws_m + (size_t)NB * NCH * 12;

    pred_kernel<<<1024, 256, 0, stream>>>(x, W, bias, out);
    crf_scan_kernel<<<(NB * NCH * 3) / 256, 256, 0, stream>>>(out, y, trans, ws_m, ws_p);
    crf_combine_kernel<<<1, 128, 0, stream>>>(out, y, ws_m, ws_p, startt, stopt, loss_out);
}